// Round 3
// baseline (6095.990 us; speedup 1.0000x reference)
//
#include <hip/hip_runtime.h>
#include <hip/hip_bf16.h>

// Problem constants (match reference)
#define NN 100000   // nodes
#define NE 400000   // edges per etype
#define NT 3        // etypes
#define NL 3        // layers
#define DD 64       // feature dim

// mode codes for a tensor pointer: 0 = bf16, 1 = fp32, 2 = use detected flag
__device__ __forceinline__ float ldf(const void* p, size_t i, int f32) {
    return f32 ? ((const float*)p)[i]
               : __bfloat162float(((const __hip_bfloat16*)p)[i]);
}
__device__ __forceinline__ void stf(void* p, size_t i, int f32, float v) {
    if (f32) ((float*)p)[i] = v;
    else     ((__hip_bfloat16*)p)[i] = __float2bfloat16(v);
}

// Detect fp32 vs bf16 float tensors by inspecting low half-words of `feat`.
// fp32 N(0,1): low 16 bits are mantissa bits -> "bf16 exponent" ~uniform ->
// ~32/4096 hits of exp in {0,255}. bf16 N(0,1): 0 hits.
__global__ void detect_kernel(const unsigned short* __restrict__ feat16,
                              int* __restrict__ flag) {
    int cnt = 0;
    for (int i = threadIdx.x; i < 4096; i += 64) {
        unsigned short u = feat16[2 * i];
        unsigned e = (u >> 7) & 0xFF;
        if (e == 0xFF || e == 0) cnt++;
    }
    for (int o = 32; o; o >>= 1) cnt += __shfl_down(cnt, o);
    if (threadIdx.x == 0) flag[0] = (cnt >= 8) ? 1 : 0;  // 1 = fp32 data
}

__global__ __launch_bounds__(256) void deg_kernel(const int* __restrict__ dst,
                                                  float* __restrict__ deg) {
    int tid = blockIdx.x * 256 + threadIdx.x;
    if (tid >= NT * NE) return;
    int t = tid / NE;
    atomicAdd(&deg[t * NN + dst[tid]], 1.0f);
}

// agg[dst[e]][f] += h[src[e]][f]   (wave-per-edge: lane = feature)
__global__ __launch_bounds__(256) void scatter_kernel(
    const void* __restrict__ h, int h_mode, const int* __restrict__ src,
    const int* __restrict__ dst, float* __restrict__ agg,
    const int* __restrict__ flag) {
    int f32 = (h_mode == 2) ? flag[0] : h_mode;
    unsigned tid = blockIdx.x * 256 + threadIdx.x;
    unsigned e = tid >> 6;
    unsigned f = tid & 63;
    if (e >= NE) return;
    int s = src[e];
    int d = dst[e];
    float v = ldf(h, (size_t)s * DD + f, f32);
    atomicAdd(&agg[(size_t)d * DD + f], v);
}

// out[n][j] (+)= relu?( h[n]@Ws + (agg[n]/max(deg,1))@Wn + b )[j]
// wave-per-row: lane = output column j. woff/boff are ELEMENT offsets into
// W_self/W_neigh/bias, applied after dtype resolution.
__global__ __launch_bounds__(256) void sage_gemm(
    const void* __restrict__ h, int h_mode, const float* __restrict__ agg,
    const float* __restrict__ deg, const void* __restrict__ Ws,
    const void* __restrict__ Wn, const void* __restrict__ bias,
    size_t woff, size_t boff, void* __restrict__ out, int out_mode,
    int relu, int acc_flag, const int* __restrict__ flag) {
    int wf = flag[0];
    int hf = (h_mode == 2) ? wf : h_mode;
    int of = (out_mode == 2) ? wf : out_mode;
    unsigned tid = blockIdx.x * 256 + threadIdx.x;
    unsigned n = tid >> 6;
    unsigned j = tid & 63;
    if (n >= NN) return;
    float invd = 1.0f / fmaxf(deg[n], 1.0f);
    const float* arow = agg + (size_t)n * DD;
    float accs = 0.f, accn = 0.f;
#pragma unroll
    for (int k = 0; k < DD; ++k) {
        float hv = ldf(h, (size_t)n * DD + k, hf);
        accs += hv * ldf(Ws, woff + (size_t)k * DD + j, wf);
        accn += arow[k] * ldf(Wn, woff + (size_t)k * DD + j, wf);
    }
    float r = accs + accn * invd + ldf(bias, boff + j, wf);
    if (relu) r = fmaxf(r, 0.f);
    if (acc_flag) r += ldf(out, tid, of);
    stf(out, tid, of, r);
}

extern "C" void kernel_launch(void* const* d_in, const int* in_sizes, int n_in,
                              void* d_out, int out_size, void* d_ws, size_t ws_size,
                              hipStream_t stream) {
    const void* feat    = d_in[0];
    const void* W_self  = d_in[1];
    const void* W_neigh = d_in[2];
    const void* bias    = d_in[3];
    const int* src = (const int*)d_in[4];
    const int* dst = (const int*)d_in[5];

    const size_t ND = (size_t)NN * DD;
    // ws layout (~52.5 MB):
    //   flag int[16]    @ 0
    //   deg  f32[NT*NN] @ 64 B
    //   agg  f32[ND]
    //   X    f32[ND]    -- layer-1 intermediate, always fp32
    int* flag = (int*)d_ws;
    float* deg = (float*)((char*)d_ws + 64);
    float* agg = deg + (size_t)NT * NN;
    float* X   = agg + ND;

    detect_kernel<<<1, 64, 0, stream>>>((const unsigned short*)feat, flag);

    hipMemsetAsync(deg, 0, (size_t)NT * NN * sizeof(float), stream);
    deg_kernel<<<(NT * NE + 255) / 256, 256, 0, stream>>>(dst, deg);

    // layer dataflow: feat -> d_out -> X -> d_out (no intra-layer aliasing)
    const void* hin[NL]  = {feat, d_out, X};
    const int  hin_m[NL] = {2, 2, 1};
    void*      hout[NL]  = {d_out, X, d_out};
    const int hout_m[NL] = {2, 1, 2};

    for (int l = 0; l < NL; ++l) {
        for (int t = 0; t < NT; ++t) {
            hipMemsetAsync(agg, 0, ND * sizeof(float), stream);
            scatter_kernel<<<(NE * DD) / 256, 256, 0, stream>>>(
                hin[l], hin_m[l], src + (size_t)t * NE, dst + (size_t)t * NE,
                agg, flag);
            sage_gemm<<<(NN * DD + 255) / 256, 256, 0, stream>>>(
                hin[l], hin_m[l], agg, deg + (size_t)t * NN,
                W_self, W_neigh, bias,
                (size_t)(l * NT + t) * DD * DD, (size_t)(l * NT + t) * DD,
                hout[l], hout_m[l], (l < NL - 1) ? 1 : 0, (t > 0) ? 1 : 0,
                flag);
        }
    }
}

// Round 4
// 1286.469 us; speedup vs baseline: 4.7385x; 4.7385x over previous
//
#include <hip/hip_runtime.h>
#include <hip/hip_bf16.h>

// Problem constants (match reference)
#define NN 100000   // nodes
#define NE 400000   // edges per etype
#define NT 3        // etypes
#define NL 3        // layers
#define DD 64       // feature dim

// Data established as fp32 (round-3 runtime detection: bf16 interp NaN'd,
// detected-fp32 path passed with absmax 7.8e-3).

__global__ __launch_bounds__(256) void deg_kernel(const int* __restrict__ dst,
                                                  float* __restrict__ deg) {
    int tid = blockIdx.x * 256 + threadIdx.x;
    if (tid >= NT * NE) return;
    int t = tid / NE;
    atomicAdd(&deg[t * NN + dst[tid]], 1.0f);
}

// agg[dst[e]][f] += h[src[e]][f]   (wave-per-edge: lane = feature)
__global__ __launch_bounds__(256) void scatter_kernel(
    const float* __restrict__ h, const int* __restrict__ src,
    const int* __restrict__ dst, float* __restrict__ agg) {
    unsigned tid = blockIdx.x * 256 + threadIdx.x;
    unsigned e = tid >> 6;
    unsigned f = tid & 63;
    if (e >= NE) return;
    int s = src[e];
    int d = dst[e];
    atomicAdd(&agg[(size_t)d * DD + f], h[(size_t)s * DD + f]);
}

// Tiled fused SAGE epilogue GEMM:
//   out[n][j] (+)= relu?( h[n]@Ws + (agg[n]*invd[n])@Wn + b )[j]
// Block: 64 rows x 64 cols, K=128 ([h | agg*invd] @ [Ws; Wn]).
// LDS: A_s 64x132 f32 (33.8KB, +4 pad for banks/alignment), W_s 128x64 (32KB).
// Thread (256/block): 4x4 register tile; wave w rows w*16+r0+{0,4,8,12},
// cols 4*c0+{0..3}. All LDS reads ds_read_b128, broadcast or <=2-way banked.
__global__ __launch_bounds__(256) void sage_gemm(
    const float* __restrict__ h, const float* __restrict__ agg,
    const float* __restrict__ deg, const float* __restrict__ Ws,
    const float* __restrict__ Wn, const float* __restrict__ bias,
    float* __restrict__ out, int relu, int acc_flag) {
    __shared__ __align__(16) float A_s[64][132];
    __shared__ __align__(16) float W_s[128][64];

    const int tx = threadIdx.x;
    const int n0 = blockIdx.x * 64;
    const int rr = tx >> 4;          // 0..15 (row within 16-row group)
    const int k0 = (tx & 15) * 4;    // float4 column offset 0..60

    // ---- stage tiles ----
#pragma unroll
    for (int q = 0; q < 4; ++q) {
        int r = rr + 16 * q;         // 0..63
        int n = n0 + r;
        float4 hv = make_float4(0.f, 0.f, 0.f, 0.f);
        float4 av = make_float4(0.f, 0.f, 0.f, 0.f);
        if (n < NN) {
            hv = *(const float4*)&h[(size_t)n * DD + k0];
            av = *(const float4*)&agg[(size_t)n * DD + k0];
            float invd = 1.0f / fmaxf(deg[n], 1.0f);
            av.x *= invd; av.y *= invd; av.z *= invd; av.w *= invd;
        }
        *(float4*)&A_s[r][k0]      = hv;
        *(float4*)&A_s[r][64 + k0] = av;
        // weights: element (k=r, j=k0..k0+3)
        *(float4*)&W_s[r][k0]      = *(const float4*)&Ws[(size_t)r * DD + k0];
        *(float4*)&W_s[64 + r][k0] = *(const float4*)&Wn[(size_t)r * DD + k0];
    }
    __syncthreads();

    // ---- compute 4x4 per thread ----
    const int lane = tx & 63, w = tx >> 6;
    const int c0 = (lane & 15) * 4;        // cols c0..c0+3
    const int r0 = lane >> 4;              // 0..3
    const int rbase = w * 16 + r0;         // rows rbase + 4*i

    float acc[4][4];
#pragma unroll
    for (int i = 0; i < 4; ++i)
#pragma unroll
        for (int j = 0; j < 4; ++j) acc[i][j] = 0.f;

    for (int k = 0; k < 128; k += 4) {
        float4 av[4], wv[4];
#pragma unroll
        for (int i = 0; i < 4; ++i)
            av[i] = *(const float4*)&A_s[rbase + 4 * i][k];
#pragma unroll
        for (int kk = 0; kk < 4; ++kk)
            wv[kk] = *(const float4*)&W_s[k + kk][c0];
#pragma unroll
        for (int i = 0; i < 4; ++i) {
            const float* a = (const float*)&av[i];
#pragma unroll
            for (int kk = 0; kk < 4; ++kk) {
                const float* ww = (const float*)&wv[kk];
                acc[i][0] += a[kk] * ww[0];
                acc[i][1] += a[kk] * ww[1];
                acc[i][2] += a[kk] * ww[2];
                acc[i][3] += a[kk] * ww[3];
            }
        }
    }

    // ---- epilogue ----
    float4 b4 = *(const float4*)&bias[c0];
#pragma unroll
    for (int i = 0; i < 4; ++i) {
        int n = n0 + rbase + 4 * i;
        if (n >= NN) continue;
        float4 r4;
        r4.x = acc[i][0] + b4.x; r4.y = acc[i][1] + b4.y;
        r4.z = acc[i][2] + b4.z; r4.w = acc[i][3] + b4.w;
        if (relu) {
            r4.x = fmaxf(r4.x, 0.f); r4.y = fmaxf(r4.y, 0.f);
            r4.z = fmaxf(r4.z, 0.f); r4.w = fmaxf(r4.w, 0.f);
        }
        float* op = &out[(size_t)n * DD + c0];
        if (acc_flag) {
            float4 p = *(const float4*)op;
            r4.x += p.x; r4.y += p.y; r4.z += p.z; r4.w += p.w;
        }
        *(float4*)op = r4;
    }
}

extern "C" void kernel_launch(void* const* d_in, const int* in_sizes, int n_in,
                              void* d_out, int out_size, void* d_ws, size_t ws_size,
                              hipStream_t stream) {
    const float* feat    = (const float*)d_in[0];
    const float* W_self  = (const float*)d_in[1];
    const float* W_neigh = (const float*)d_in[2];
    const float* bias    = (const float*)d_in[3];
    const int* src = (const int*)d_in[4];
    const int* dst = (const int*)d_in[5];
    float* out = (float*)d_out;

    const size_t ND = (size_t)NN * DD;
    // ws layout (~52.5 MB): deg f32[NT*NN] | agg f32[ND] | X f32[ND]
    float* deg = (float*)d_ws;
    float* agg = deg + (size_t)NT * NN;
    float* X   = agg + ND;

    hipMemsetAsync(deg, 0, (size_t)NT * NN * sizeof(float), stream);
    deg_kernel<<<(NT * NE + 255) / 256, 256, 0, stream>>>(dst, deg);

    // layer dataflow: feat -> d_out -> X -> d_out (no intra-layer aliasing)
    const float* hin[NL]  = {feat, out, X};
    float*       hout[NL] = {out, X, out};
    const int ngrid = (NN + 63) / 64;

    for (int l = 0; l < NL; ++l) {
        for (int t = 0; t < NT; ++t) {
            hipMemsetAsync(agg, 0, ND * sizeof(float), stream);
            scatter_kernel<<<(NE * DD) / 256, 256, 0, stream>>>(
                hin[l], src + (size_t)t * NE, dst + (size_t)t * NE, agg);
            sage_gemm<<<ngrid, 256, 0, stream>>>(
                hin[l], agg, deg + (size_t)t * NN,
                W_self  + (size_t)(l * NT + t) * DD * DD,
                W_neigh + (size_t)(l * NT + t) * DD * DD,
                bias    + (size_t)(l * NT + t) * DD,
                hout[l], (l < NL - 1) ? 1 : 0, (t > 0) ? 1 : 0);
        }
    }
}

// Round 5
// 820.564 us; speedup vs baseline: 7.4290x; 1.5678x over previous
//
#include <hip/hip_runtime.h>
#include <hip/hip_bf16.h>

// Problem constants (match reference)
#define NN 100000   // nodes
#define NE 400000   // edges per etype
#define NT 3        // etypes
#define NL 3        // layers
#define DD 64       // feature dim
#define M_TOT (NT * NN)             // 300000 concatenated (etype,node) rows
#define NBLK ((M_TOT + 255) / 256)  // 1172 scan blocks

// Data established as fp32 (round-3 runtime dtype detection).

// ---- CSR build (once per launch; dst is layer-invariant) -------------------

__global__ __launch_bounds__(256) void count_kernel(const int* __restrict__ dst,
                                                    int* __restrict__ cnt) {
    int tid = blockIdx.x * 256 + threadIdx.x;
    if (tid >= NT * NE) return;
    int t = tid / NE;
    atomicAdd(&cnt[t * NN + dst[tid]], 1);
}

__global__ __launch_bounds__(256) void bsum_kernel(const int* __restrict__ cnt,
                                                   int* __restrict__ bsums) {
    __shared__ int s[256];
    int i = blockIdx.x * 256 + threadIdx.x;
    s[threadIdx.x] = (i < M_TOT) ? cnt[i] : 0;
    __syncthreads();
    for (int o = 128; o; o >>= 1) {
        if (threadIdx.x < o) s[threadIdx.x] += s[threadIdx.x + o];
        __syncthreads();
    }
    if (threadIdx.x == 0) bsums[blockIdx.x] = s[0];
}

// exclusive scan of bsums[NBLK] in-place, single block
__global__ void scan_bsums_kernel(int* __restrict__ b) {
    __shared__ int s[256];
    __shared__ int carry;
    if (threadIdx.x == 0) carry = 0;
    __syncthreads();
    for (int base = 0; base < NBLK; base += 256) {
        int i = base + threadIdx.x;
        int v = (i < NBLK) ? b[i] : 0;
        s[threadIdx.x] = v;
        __syncthreads();
        for (int o = 1; o < 256; o <<= 1) {          // Hillis-Steele inclusive
            int t = (threadIdx.x >= o) ? s[threadIdx.x - o] : 0;
            __syncthreads();
            s[threadIdx.x] += t;
            __syncthreads();
        }
        int excl = s[threadIdx.x] - v + carry;
        if (i < NBLK) b[i] = excl;
        __syncthreads();
        if (threadIdx.x == 0) carry += s[255];
        __syncthreads();
    }
}

// rs[i] = exclusive scan of cnt (+ rs[M_TOT] = total)
__global__ __launch_bounds__(256) void row_start_kernel(
    const int* __restrict__ cnt, const int* __restrict__ bsums,
    int* __restrict__ rs) {
    __shared__ int s[256];
    int i = blockIdx.x * 256 + threadIdx.x;
    int v = (i < M_TOT) ? cnt[i] : 0;
    s[threadIdx.x] = v;
    __syncthreads();
    for (int o = 1; o < 256; o <<= 1) {
        int t = (threadIdx.x >= o) ? s[threadIdx.x - o] : 0;
        __syncthreads();
        s[threadIdx.x] += t;
        __syncthreads();
    }
    int excl = s[threadIdx.x] - v + bsums[blockIdx.x];
    if (i < M_TOT) rs[i] = excl;
    if (i == M_TOT - 1) rs[M_TOT] = excl + v;
}

__global__ __launch_bounds__(256) void fill_kernel(
    const int* __restrict__ src, const int* __restrict__ dst,
    int* __restrict__ cursor, int* __restrict__ col) {
    int tid = blockIdx.x * 256 + threadIdx.x;
    if (tid >= NT * NE) return;
    int t = tid / NE;
    int slot = atomicAdd(&cursor[t * NN + dst[tid]], 1);
    col[slot] = src[tid];
}

// ---- per-(layer,etype) aggregation: pull-mode mean gather (no atomics) -----
// wave-per-node, lane = feature. 4-wide unrolled independent row loads.
__global__ __launch_bounds__(256) void gather_kernel(
    const float* __restrict__ h, const int* __restrict__ rs,
    const int* __restrict__ col, float* __restrict__ mean) {
    int w = blockIdx.x * 4 + (threadIdx.x >> 6);   // node
    if (w >= NN) return;
    int f = threadIdx.x & 63;                      // feature
    int start = rs[w], end = rs[w + 1];
    float acc = 0.f;
    int e = start;
    for (; e + 4 <= end; e += 4) {
        int s0 = col[e], s1 = col[e + 1], s2 = col[e + 2], s3 = col[e + 3];
        float v0 = h[(size_t)s0 * DD + f];
        float v1 = h[(size_t)s1 * DD + f];
        float v2 = h[(size_t)s2 * DD + f];
        float v3 = h[(size_t)s3 * DD + f];
        acc += (v0 + v1) + (v2 + v3);
    }
    for (; e < end; ++e) acc += h[(size_t)col[e] * DD + f];
    float invd = (end > start) ? 1.0f / (float)(end - start) : 0.f;
    mean[(size_t)w * DD + f] = acc * invd;
}

// ---- tiled fused SAGE epilogue GEMM ----------------------------------------
//   out[n][j] (+)= relu?( h[n]@Ws + mean[n]@Wn + b )[j]
// Block: 64x64 tile, K=128 ([h | mean] @ [Ws; Wn]); LDS A_s 64x132, W_s 128x64.
__global__ __launch_bounds__(256) void sage_gemm(
    const float* __restrict__ h, const float* __restrict__ mean,
    const float* __restrict__ Ws, const float* __restrict__ Wn,
    const float* __restrict__ bias, float* __restrict__ out,
    int relu, int acc_flag) {
    __shared__ __align__(16) float A_s[64][132];
    __shared__ __align__(16) float W_s[128][64];

    const int tx = threadIdx.x;
    const int n0 = blockIdx.x * 64;
    const int rr = tx >> 4;
    const int k0 = (tx & 15) * 4;

#pragma unroll
    for (int q = 0; q < 4; ++q) {
        int r = rr + 16 * q;
        int n = n0 + r;
        float4 hv = make_float4(0.f, 0.f, 0.f, 0.f);
        float4 av = make_float4(0.f, 0.f, 0.f, 0.f);
        if (n < NN) {
            hv = *(const float4*)&h[(size_t)n * DD + k0];
            av = *(const float4*)&mean[(size_t)n * DD + k0];
        }
        *(float4*)&A_s[r][k0]      = hv;
        *(float4*)&A_s[r][64 + k0] = av;
        *(float4*)&W_s[r][k0]      = *(const float4*)&Ws[(size_t)r * DD + k0];
        *(float4*)&W_s[64 + r][k0] = *(const float4*)&Wn[(size_t)r * DD + k0];
    }
    __syncthreads();

    const int lane = tx & 63, w = tx >> 6;
    const int c0 = (lane & 15) * 4;
    const int r0 = lane >> 4;
    const int rbase = w * 16 + r0;

    float acc[4][4];
#pragma unroll
    for (int i = 0; i < 4; ++i)
#pragma unroll
        for (int j = 0; j < 4; ++j) acc[i][j] = 0.f;

    for (int k = 0; k < 128; k += 4) {
        float4 av[4], wv[4];
#pragma unroll
        for (int i = 0; i < 4; ++i)
            av[i] = *(const float4*)&A_s[rbase + 4 * i][k];
#pragma unroll
        for (int kk = 0; kk < 4; ++kk)
            wv[kk] = *(const float4*)&W_s[k + kk][c0];
#pragma unroll
        for (int i = 0; i < 4; ++i) {
            const float* a = (const float*)&av[i];
#pragma unroll
            for (int kk = 0; kk < 4; ++kk) {
                const float* ww = (const float*)&wv[kk];
                acc[i][0] += a[kk] * ww[0];
                acc[i][1] += a[kk] * ww[1];
                acc[i][2] += a[kk] * ww[2];
                acc[i][3] += a[kk] * ww[3];
            }
        }
    }

    float4 b4 = *(const float4*)&bias[c0];
#pragma unroll
    for (int i = 0; i < 4; ++i) {
        int n = n0 + rbase + 4 * i;
        if (n >= NN) continue;
        float4 r4;
        r4.x = acc[i][0] + b4.x; r4.y = acc[i][1] + b4.y;
        r4.z = acc[i][2] + b4.z; r4.w = acc[i][3] + b4.w;
        if (relu) {
            r4.x = fmaxf(r4.x, 0.f); r4.y = fmaxf(r4.y, 0.f);
            r4.z = fmaxf(r4.z, 0.f); r4.w = fmaxf(r4.w, 0.f);
        }
        float* op = &out[(size_t)n * DD + c0];
        if (acc_flag) {
            float4 p = *(const float4*)op;
            r4.x += p.x; r4.y += p.y; r4.z += p.z; r4.w += p.w;
        }
        *(float4*)op = r4;
    }
}

extern "C" void kernel_launch(void* const* d_in, const int* in_sizes, int n_in,
                              void* d_out, int out_size, void* d_ws, size_t ws_size,
                              hipStream_t stream) {
    const float* feat    = (const float*)d_in[0];
    const float* W_self  = (const float*)d_in[1];
    const float* W_neigh = (const float*)d_in[2];
    const float* bias    = (const float*)d_in[3];
    const int* src = (const int*)d_in[4];
    const int* dst = (const int*)d_in[5];
    float* out = (float*)d_out;

    const size_t ND = (size_t)NN * DD;
    // ws layout (int-element offsets; ~59.6 MB total):
    //   cnt  [300000] @0 | rs [300008] @300000 | cursor [300000] @600008
    //   bsums[1176] @900008 | col [1200000] @901184
    //   meanbuf f32[ND] @2101184 (byte 8404736, 16B-aligned)
    //   X       f32[ND] @8501184
    int* base = (int*)d_ws;
    int* cnt    = base;
    int* rs     = base + 300000;
    int* cursor = base + 600008;
    int* bsums  = base + 900008;
    int* col    = base + 901184;
    float* meanbuf = (float*)(base + 2101184);
    float* X       = (float*)(base + 8501184);

    // ---- CSR build (once; reused across layers) ----
    hipMemsetAsync(cnt, 0, (size_t)M_TOT * sizeof(int), stream);
    count_kernel<<<(NT * NE + 255) / 256, 256, 0, stream>>>(dst, cnt);
    bsum_kernel<<<NBLK, 256, 0, stream>>>(cnt, bsums);
    scan_bsums_kernel<<<1, 256, 0, stream>>>(bsums);
    row_start_kernel<<<NBLK, 256, 0, stream>>>(cnt, bsums, rs);
    hipMemcpyAsync(cursor, rs, (size_t)M_TOT * sizeof(int),
                   hipMemcpyDeviceToDevice, stream);
    fill_kernel<<<(NT * NE + 255) / 256, 256, 0, stream>>>(src, dst, cursor, col);

    // layer dataflow: feat -> d_out -> X -> d_out (no intra-layer aliasing)
    const float* hin[NL]  = {feat, out, X};
    float*       hout[NL] = {out, X, out};
    const int ggrid = (NN + 3) / 4;
    const int mgrid = (NN + 63) / 64;

    for (int l = 0; l < NL; ++l) {
        for (int t = 0; t < NT; ++t) {
            gather_kernel<<<ggrid, 256, 0, stream>>>(
                hin[l], rs + (size_t)t * NN, col, meanbuf);
            sage_gemm<<<mgrid, 256, 0, stream>>>(
                hin[l], meanbuf,
                W_self  + (size_t)(l * NT + t) * DD * DD,
                W_neigh + (size_t)(l * NT + t) * DD * DD,
                bias    + (size_t)(l * NT + t) * DD,
                hout[l], (l < NL - 1) ? 1 : 0, (t > 0) ? 1 : 0);
        }
    }
}